// Round 1
// baseline (1114.734 us; speedup 1.0000x reference)
//
#include <hip/hip_runtime.h>
#include <hip/hip_bf16.h>
#include <math.h>

#define N_NODES 10000
#define FDIM 128
#define HDIM 64
#define NEDGES 320000
#define M_EDGES (NEDGES + N_NODES)   // 330000 (with self-loops)

typedef __attribute__((ext_vector_type(8))) short short8;   // 8 bf16
typedef __attribute__((ext_vector_type(4))) float floatx4;

__device__ __forceinline__ float lrelu(float v, float s){ return v >= 0.f ? v : s*v; }

// ---------------- CSR build ----------------
__global__ void k_count(const int* __restrict__ ep, const int* __restrict__ eh,
                        int* __restrict__ ptr_p, int* __restrict__ ptr_h){
  int idx = blockIdx.x*blockDim.x + threadIdx.x;
  if (idx >= 2*M_EDGES) return;
  int list = idx >= M_EDGES;
  int e = idx - list*M_EDGES;
  const int* el = list ? eh : ep;
  int* ptr = list ? ptr_h : ptr_p;
  int dst = (e < NEDGES) ? el[NEDGES + e] : (e - NEDGES);
  atomicAdd(&ptr[dst+1], 1);
}

__global__ void k_scan(int* __restrict__ ptr_p, int* __restrict__ cur_p,
                       int* __restrict__ ptr_h, int* __restrict__ cur_h){
  __shared__ int wsum[4];
  __shared__ int carry;
  int t = threadIdx.x, wid = t>>6, lane = t&63;
  for (int a = 0; a < 2; ++a){
    int* ptr = a ? ptr_h : ptr_p;
    int* cur = a ? cur_h : cur_p;
    if (t == 0) carry = 0;
    __syncthreads();
    for (int base = 0; base <= N_NODES; base += 256){
      int i = base + t;
      int v = (i <= N_NODES) ? ptr[i] : 0;
      int sc = v;
      #pragma unroll
      for (int off=1; off<64; off<<=1){ int u = __shfl_up(sc, off); if (lane >= off) sc += u; }
      if (lane == 63) wsum[wid] = sc;
      __syncthreads();
      int wo = 0;
      for (int w = 0; w < wid; ++w) wo += wsum[w];
      int val = carry + wo + sc;
      if (i <= N_NODES) ptr[i] = val;
      if (i <  N_NODES) cur[i] = val;
      __syncthreads();
      if (t == 0) carry += wsum[0]+wsum[1]+wsum[2]+wsum[3];
      __syncthreads();
    }
  }
}

__global__ void k_fill(const int* __restrict__ ep, const int* __restrict__ eh,
                       int* __restrict__ cur_p, int* __restrict__ cur_h,
                       int* __restrict__ src_p, int* __restrict__ src_h){
  int idx = blockIdx.x*blockDim.x + threadIdx.x;
  if (idx >= 2*M_EDGES) return;
  int list = idx >= M_EDGES;
  int e = idx - list*M_EDGES;
  const int* el = list ? eh : ep;
  int* cur  = list ? cur_h : cur_p;
  int* sarr = list ? src_h : src_p;
  int src, dst;
  if (e < NEDGES){ src = el[e]; dst = el[NEDGES+e]; } else { src = dst = e - NEDGES; }
  int pos = atomicAdd(&cur[dst], 1);
  sarr[pos] = src;
}

__global__ void k_masksum(const int* __restrict__ tm, float* __restrict__ misc){
  __shared__ int ssum[4];
  int idx = blockIdx.x*blockDim.x + threadIdx.x;
  int c = 0;
  for (int i = idx; i < N_NODES; i += gridDim.x*blockDim.x) c += (tm[i] > 0);
  #pragma unroll
  for (int off=32; off; off>>=1) c += __shfl_down(c, off);
  if ((threadIdx.x & 63) == 0) ssum[threadIdx.x>>6] = c;
  __syncthreads();
  if (threadIdx.x == 0) atomicAdd(&misc[1], (float)(ssum[0]+ssum[1]+ssum[2]+ssum[3]));
}

// ---------------- GAT layer 1: h = x@W1, al/ar ----------------
__global__ __launch_bounds__(256) void k_gemm1(const float* __restrict__ x, const float* __restrict__ W1,
    const float* __restrict__ asrc, const float* __restrict__ adst,
    float* __restrict__ h, float* __restrict__ al, float* __restrict__ ar){
  int wid = threadIdx.x>>6, lane = threadIdx.x&63;
  int r = blockIdx.x*4 + wid;
  if (r >= N_NODES) return;
  const float* xr = x + (size_t)r*FDIM;
  float xv0 = xr[lane], xv1 = xr[64+lane];
  float acc = 0.f;
  #pragma unroll 16
  for (int k=0;k<64;k++) acc = fmaf(__shfl(xv0,k), W1[k*HDIM+lane], acc);
  #pragma unroll 16
  for (int k=0;k<64;k++) acc = fmaf(__shfl(xv1,k), W1[(64+k)*HDIM+lane], acc);
  h[(size_t)r*HDIM + lane] = acc;
  float pa = acc*asrc[lane], pb = acc*adst[lane];
  #pragma unroll
  for (int off=32; off; off>>=1){ pa += __shfl_down(pa,off); pb += __shfl_down(pb,off); }
  if (lane==0){ al[r]=pa; ar[r]=pb; }
}

// ---------------- GAT1 aggregate + affine + lrelu + GEMM2 + al2/ar2 ----------------
__global__ __launch_bounds__(256) void k_gat1(const int* __restrict__ ptr, const int* __restrict__ srcarr,
    const float* __restrict__ al, const float* __restrict__ ar, const float* __restrict__ h,
    const float* __restrict__ b1, const float* __restrict__ gam, const float* __restrict__ bet,
    const float* __restrict__ W2, const float* __restrict__ asrc2, const float* __restrict__ adst2,
    float* __restrict__ h2, float* __restrict__ al2, float* __restrict__ ar2){
  int wid = threadIdx.x>>6, lane = threadIdx.x&63;
  int n = blockIdx.x*4 + wid;
  if (n >= N_NODES) return;
  int s0 = ptr[n], s1 = ptr[n+1];
  float arn = ar[n];
  // online softmax (lanes = edges)
  float m_l = -3.0e38f, s_l = 0.f;
  for (int idx = s0+lane; idx < s1; idx += 64){
    int sj = srcarr[idx];
    float a = lrelu(al[sj]+arn, 0.2f);
    if (a > m_l){ s_l *= __expf(m_l - a); m_l = a; }
    s_l += __expf(a - m_l);
  }
  #pragma unroll
  for (int off=32; off; off>>=1){
    float mo = __shfl_down(m_l, off), so = __shfl_down(s_l, off);
    float mn = fmaxf(m_l, mo);
    s_l = s_l*__expf(m_l-mn) + so*__expf(mo-mn);
    m_l = mn;
  }
  float m = __shfl(m_l, 0);
  float inv_s = 1.f/(__shfl(s_l, 0) + 1e-16f);
  // aggregation (lanes = H columns, sequential edges)
  float acc = 0.f;
  for (int idx = s0; idx < s1; ++idx){
    int sj = srcarr[idx];
    float a = lrelu(al[sj]+arn, 0.2f);
    float w = __expf(a - m)*inv_s;
    acc = fmaf(w, h[(size_t)sj*HDIM + lane], acc);
  }
  float hid = acc + b1[lane];
  hid = hid*(gam[lane]*0.9999950000374997f) + bet[lane];   // gamma/sqrt(1+1e-5)
  hid = lrelu(hid, 0.01f);
  // GEMM2: (1x64)@(64x2) via shfl reduce
  float t0 = hid*W2[lane*2+0], t1 = hid*W2[lane*2+1];
  #pragma unroll
  for (int off=32; off; off>>=1){ t0 += __shfl_down(t0,off); t1 += __shfl_down(t1,off); }
  if (lane==0){
    h2[n*2+0] = t0; h2[n*2+1] = t1;
    al2[n] = t0*asrc2[0] + t1*asrc2[1];
    ar2[n] = t0*adst2[0] + t1*adst2[1];
  }
}

// ---------------- GAT2 aggregate + log_softmax + loss/node_p partials ----------------
__global__ __launch_bounds__(256) void k_gat2(const int* __restrict__ ptr, const int* __restrict__ srcarr,
    const float* __restrict__ al2, const float* __restrict__ ar2, const float* __restrict__ h2,
    const float* __restrict__ b2, const int* __restrict__ y, const int* __restrict__ tm,
    float* __restrict__ np_acc, float* __restrict__ misc){
  __shared__ float lbuf[4];
  int wid = threadIdx.x>>6, lane = threadIdx.x&63;
  int n = blockIdx.x*4 + wid;
  float lval = 0.f;
  if (n < N_NODES){
    int s0 = ptr[n], s1 = ptr[n+1];
    float arn = ar2[n];
    float m_l = -3.0e38f, s_l = 0.f;
    for (int idx = s0+lane; idx < s1; idx += 64){
      int sj = srcarr[idx];
      float a = lrelu(al2[sj]+arn, 0.2f);
      if (a > m_l){ s_l *= __expf(m_l - a); m_l = a; }
      s_l += __expf(a - m_l);
    }
    #pragma unroll
    for (int off=32; off; off>>=1){
      float mo = __shfl_down(m_l, off), so = __shfl_down(s_l, off);
      float mn = fmaxf(m_l, mo);
      s_l = s_l*__expf(m_l-mn) + so*__expf(mo-mn);
      m_l = mn;
    }
    float m = __shfl(m_l, 0);
    float sden = __shfl(s_l, 0) + 1e-16f;
    float a0 = 0.f, a1 = 0.f;
    for (int idx = s0+lane; idx < s1; idx += 64){
      int sj = srcarr[idx];
      float a = lrelu(al2[sj]+arn, 0.2f);
      float w = __expf(a - m);
      a0 = fmaf(w, h2[sj*2+0], a0);
      a1 = fmaf(w, h2[sj*2+1], a1);
    }
    #pragma unroll
    for (int off=32; off; off>>=1){ a0 += __shfl_down(a0,off); a1 += __shfl_down(a1,off); }
    if (lane == 0){
      float o0 = a0/sden + b2[0], o1 = a1/sden + b2[1];
      float mx = fmaxf(o0, o1);
      float lse = mx + logf(__expf(o0-mx) + __expf(o1-mx));
      float lp0 = o0 - lse, lp1 = o1 - lse;
      np_acc[n] += __expf(lp1);
      float pick = (y[n] == 0) ? lp0 : lp1;
      lval = (tm[n] > 0) ? -pick : 0.f;
    }
  }
  if (lane == 0) lbuf[wid] = lval;
  __syncthreads();
  if (threadIdx.x == 0){
    float tt = lbuf[0]+lbuf[1]+lbuf[2]+lbuf[3];
    atomicAdd(&misc[0], tt);
  }
}

// ---------------- feature gates: keep*sigmoid(emb_w), pw ----------------
__global__ void k_f(const float* __restrict__ logit_p, const float* __restrict__ emb_w,
                    float* __restrict__ keepsw, float* __restrict__ pw_out){
  int f = threadIdx.x;
  const float EPSF = 2.2204460492503131e-16f;
  float p = 1.f/(1.f + __expf(-logit_p[f]));
  float approx = logf(p + EPSF) - logf(1.f - p + EPSF);   // + log(.5+eps)-log(.5+eps)==0
  float keep = 1.f - 1.f/(1.f + __expf(-approx*10.f));
  keepsw[f] = keep * (1.f/(1.f + __expf(-emb_w[f])));
  pw_out[f] = 1.f - p;
}

// ---------------- ex (bf16) + row sums ----------------
__global__ __launch_bounds__(256) void k_ex(const float* __restrict__ x, const float* __restrict__ keepsw,
                                            __hip_bfloat16* __restrict__ exb, float* __restrict__ denom){
  int wid = threadIdx.x>>6, lane = threadIdx.x&63;
  int r = blockIdx.x*4 + wid;
  if (r >= N_NODES) return;
  const float* xr = x + (size_t)r*FDIM;
  float v0 = xr[lane]*keepsw[lane];
  float v1 = xr[64+lane]*keepsw[64+lane];
  exb[(size_t)r*FDIM + lane]      = __float2bfloat16(v0);
  exb[(size_t)r*FDIM + 64 + lane] = __float2bfloat16(v1);
  float sr = v0 + v1;
  #pragma unroll
  for (int off=32; off; off>>=1) sr += __shfl_down(sr, off);
  if (lane == 0) denom[r] = sr + 1e-6f;
}

__global__ void k_npfin(const float* __restrict__ np_acc, const float* __restrict__ denom,
                        const float* __restrict__ misc, float* __restrict__ out_np,
                        float* __restrict__ out_loss, float* __restrict__ scale){
  int i = blockIdx.x*blockDim.x + threadIdx.x;
  if (i < N_NODES){
    float npv = np_acc[i]*0.25f;
    out_np[i] = npv;
    scale[i] = (2.f*npv - 1.f)/denom[i];
  }
  if (i == 0) out_loss[0] = misc[0]/(misc[1]*4.f);
}

// ---------------- w2[f] = sum_j ex[j,f]*scale[j] ----------------
__global__ __launch_bounds__(256) void k_w2(const float* __restrict__ x, const float* __restrict__ keepsw,
                                            const float* __restrict__ scale, float* __restrict__ w2){
  __shared__ float sred[256];
  int t = threadIdx.x, f = t & 127, half = t >> 7;
  float acc = 0.f;
  for (int j2 = blockIdx.x; j2 < N_NODES/2; j2 += gridDim.x){
    int j = j2*2 + half;
    acc = fmaf(x[(size_t)j*FDIM + f], scale[j], acc);
  }
  sred[t] = acc;
  __syncthreads();
  if (t < 128) atomicAdd(&w2[f], (sred[t] + sred[t+128])*keepsw[f]);
}

// ---------------- norm1[i] = sigmoid(ex_i . w2) ----------------
__global__ __launch_bounds__(256) void k_t(const float* __restrict__ x, const float* __restrict__ keepsw,
                                           const float* __restrict__ w2, float* __restrict__ out_norm1){
  int wid = threadIdx.x>>6, lane = threadIdx.x&63;
  int r = blockIdx.x*4 + wid;
  if (r >= N_NODES) return;
  const float* xr = x + (size_t)r*FDIM;
  float tv = xr[lane]*keepsw[lane]*w2[lane] + xr[64+lane]*keepsw[64+lane]*w2[64+lane];
  #pragma unroll
  for (int off=32; off; off>>=1) tv += __shfl_down(tv, off);
  if (lane == 0) out_norm1[r] = 1.f/(1.f + __expf(-tv));
}

// ---------------- graph = (ex @ ex^T) * (1/denom[j]) via bf16 MFMA ----------------
__global__ __launch_bounds__(256) void k_graph(const __hip_bfloat16* __restrict__ exb,
                                               const float* __restrict__ denom,
                                               float* __restrict__ gout){
  // XOR-swizzled LDS: 128 rows x 16 chunks of 8 bf16 (16B); chunk stored at (c ^ (r&15))
  __shared__ ushort As[128*128];
  __shared__ ushort Bs[128*128];
  int t = threadIdx.x;
  int bi = blockIdx.y, bj = blockIdx.x;
  const ushort* exu = (const ushort*)exb;
  for (int it = 0; it < 8; ++it){
    int idx = it*256 + t;
    int r = idx >> 4;
    int c = idx & 15;
    int csw = c ^ (r & 15);
    int4 va = make_int4(0,0,0,0), vb = make_int4(0,0,0,0);
    int gi = bi*128 + r;
    int gj = bj*128 + r;
    if (gi < N_NODES) va = *(const int4*)(exu + (size_t)gi*FDIM + c*8);
    if (gj < N_NODES) vb = *(const int4*)(exu + (size_t)gj*FDIM + c*8);
    *(int4*)(&As[r*128 + csw*8]) = va;
    *(int4*)(&Bs[r*128 + csw*8]) = vb;
  }
  __syncthreads();
  int wid = t>>6, lane = t&63;
  int wy = wid>>1, wx = wid&1;
  int lr = lane&15, lq = lane>>4;
  floatx4 acc[4][4];
  #pragma unroll
  for (int a=0;a<4;a++)
    #pragma unroll
    for (int b=0;b<4;b++) acc[a][b] = (floatx4){0.f,0.f,0.f,0.f};
  #pragma unroll
  for (int ks = 0; ks < 4; ++ks){
    int cidx = ks*4 + lq;              // k-chunk index 0..15
    short8 af[4], bf[4];
    #pragma unroll
    for (int a=0;a<4;a++){
      int row = wy*64 + a*16 + lr;     // row&15 == lr
      af[a] = *(const short8*)(&As[row*128 + (cidx ^ lr)*8]);
    }
    #pragma unroll
    for (int b=0;b<4;b++){
      int row = wx*64 + b*16 + lr;
      bf[b] = *(const short8*)(&Bs[row*128 + (cidx ^ lr)*8]);
    }
    #pragma unroll
    for (int a=0;a<4;a++)
      #pragma unroll
      for (int b=0;b<4;b++)
        acc[a][b] = __builtin_amdgcn_mfma_f32_16x16x32_bf16(af[a], bf[b], acc[a][b], 0, 0, 0);
  }
  #pragma unroll
  for (int b=0;b<4;b++){
    int j = bj*128 + wx*64 + b*16 + lr;
    float rden = (j < N_NODES) ? 1.f/denom[j] : 0.f;
    #pragma unroll
    for (int a=0;a<4;a++){
      int ibase = bi*128 + wy*64 + a*16 + lq*4;
      #pragma unroll
      for (int rr=0; rr<4; ++rr){
        int i = ibase + rr;
        if (i < N_NODES && j < N_NODES)
          gout[(size_t)i*N_NODES + j] = acc[a][b][rr]*rden;
      }
    }
  }
}

// ---------------- host launch ----------------
extern "C" void kernel_launch(void* const* d_in, const int* in_sizes, int n_in,
                              void* d_out, int out_size, void* d_ws, size_t ws_size,
                              hipStream_t stream) {
  (void)in_sizes; (void)n_in; (void)out_size;
  const float* x      = (const float*)d_in[0];
  const int*   y      = (const int*)  d_in[1];
  const int*   tmask  = (const int*)  d_in[2];
  const int*   ep     = (const int*)  d_in[3];
  const int*   eh     = (const int*)  d_in[4];
  const float* W1     = (const float*)d_in[5];
  const float* asrc1  = (const float*)d_in[6];
  const float* adst1  = (const float*)d_in[7];
  const float* b1     = (const float*)d_in[8];
  const float* gam    = (const float*)d_in[9];
  const float* bet    = (const float*)d_in[10];
  const float* W2     = (const float*)d_in[11];
  const float* asrc2  = (const float*)d_in[12];
  const float* adst2  = (const float*)d_in[13];
  const float* b2     = (const float*)d_in[14];
  const float* emb_w  = (const float*)d_in[15];
  const float* logitp = (const float*)d_in[16];

  // workspace layout (bytes)
  constexpr size_t SZ_N4    = 40192;          // >= (N+1)*4, 256B aligned
  constexpr size_t OFF_PTR_P = 0;
  constexpr size_t OFF_PTR_H = OFF_PTR_P + SZ_N4;
  constexpr size_t OFF_NP    = OFF_PTR_H + SZ_N4;
  constexpr size_t OFF_MISC  = OFF_NP + SZ_N4;      // misc[0]=loss, misc[1]=masksum, w2 at +256B
  constexpr size_t ZBYTES    = OFF_MISC + 2048;     // single memset covers all zero-init state
  constexpr size_t OFF_CUR_P = ZBYTES;
  constexpr size_t OFF_CUR_H = OFF_CUR_P + SZ_N4;
  constexpr size_t OFF_SRC_P = OFF_CUR_H + SZ_N4;
  constexpr size_t OFF_SRC_H = OFF_SRC_P + 1320192; // M_EDGES*4 padded
  constexpr size_t OFF_H     = OFF_SRC_H + 1320192;
  constexpr size_t OFF_AL    = OFF_H + 2560256;     // N*64*4 padded
  constexpr size_t OFF_AR    = OFF_AL + SZ_N4;
  constexpr size_t OFF_H2    = OFF_AR + SZ_N4;
  constexpr size_t OFF_AL2   = OFF_H2 + 80128;
  constexpr size_t OFF_AR2   = OFF_AL2 + SZ_N4;
  constexpr size_t OFF_EXB   = OFF_AR2 + SZ_N4;
  constexpr size_t OFF_DEN   = OFF_EXB + 2560256;   // N*128*2 padded
  constexpr size_t OFF_SCALE = OFF_DEN + SZ_N4;
  constexpr size_t OFF_KEEPSW= OFF_SCALE + SZ_N4;
  constexpr size_t WS_NEED   = OFF_KEEPSW + 512;
  if (ws_size < WS_NEED) return;

  char* ws = (char*)d_ws;
  int*   ptr_p  = (int*)  (ws + OFF_PTR_P);
  int*   ptr_h  = (int*)  (ws + OFF_PTR_H);
  float* np_acc = (float*)(ws + OFF_NP);
  float* misc   = (float*)(ws + OFF_MISC);
  float* w2v    = (float*)(ws + OFF_MISC + 256);
  int*   cur_p  = (int*)  (ws + OFF_CUR_P);
  int*   cur_h  = (int*)  (ws + OFF_CUR_H);
  int*   src_p  = (int*)  (ws + OFF_SRC_P);
  int*   src_h  = (int*)  (ws + OFF_SRC_H);
  float* hbuf   = (float*)(ws + OFF_H);
  float* al     = (float*)(ws + OFF_AL);
  float* ar     = (float*)(ws + OFF_AR);
  float* h2     = (float*)(ws + OFF_H2);
  float* al2    = (float*)(ws + OFF_AL2);
  float* ar2    = (float*)(ws + OFF_AR2);
  __hip_bfloat16* exb = (__hip_bfloat16*)(ws + OFF_EXB);
  float* denom  = (float*)(ws + OFF_DEN);
  float* scale  = (float*)(ws + OFF_SCALE);
  float* keepsw = (float*)(ws + OFF_KEEPSW);

  float* out       = (float*)d_out;
  float* out_np    = out;                // 10000
  float* out_loss  = out + 10000;        // 1
  float* out_norm  = out + 10001;        // 10000
  float* out_graph = out + 20001;        // 1e8
  float* out_pw    = out + 100020001;    // 128

  hipMemsetAsync(ws, 0, ZBYTES, stream);

  int eg = (2*M_EDGES + 255)/256;
  k_count<<<eg, 256, 0, stream>>>(ep, eh, ptr_p, ptr_h);
  k_scan<<<1, 256, 0, stream>>>(ptr_p, cur_p, ptr_h, cur_h);
  k_fill<<<eg, 256, 0, stream>>>(ep, eh, cur_p, cur_h, src_p, src_h);
  k_masksum<<<40, 256, 0, stream>>>(tmask, misc);

  for (int i = 0; i < 4; ++i){
    const int* ptr  = (i % 2 == 0) ? ptr_p : ptr_h;
    const int* sarr = (i % 2 == 0) ? src_p : src_h;
    k_gemm1<<<2500, 256, 0, stream>>>(x, W1 + (size_t)i*FDIM*HDIM, asrc1 + i*HDIM, adst1 + i*HDIM,
                                      hbuf, al, ar);
    k_gat1<<<2500, 256, 0, stream>>>(ptr, sarr, al, ar, hbuf,
                                     b1 + i*HDIM, gam + i*HDIM, bet + i*HDIM,
                                     W2 + (size_t)i*HDIM*2, asrc2 + i*2, adst2 + i*2,
                                     h2, al2, ar2);
    k_gat2<<<2500, 256, 0, stream>>>(ptr, sarr, al2, ar2, h2, b2 + i*2, y, tmask, np_acc, misc);
  }

  k_f<<<1, 128, 0, stream>>>(logitp, emb_w, keepsw, out_pw);
  k_ex<<<2500, 256, 0, stream>>>(x, keepsw, exb, denom);
  k_npfin<<<40, 256, 0, stream>>>(np_acc, denom, misc, out_np, out_loss, scale);
  k_w2<<<64, 256, 0, stream>>>(x, keepsw, scale, w2v);
  k_t<<<2500, 256, 0, stream>>>(x, keepsw, w2v, out_norm);

  dim3 gg((N_NODES + 127)/128, (N_NODES + 127)/128);
  k_graph<<<gg, 256, 0, stream>>>(exb, denom, out_graph);
}

// Round 2
// 984.489 us; speedup vs baseline: 1.1323x; 1.1323x over previous
//
#include <hip/hip_runtime.h>
#include <hip/hip_bf16.h>
#include <math.h>

#define N_NODES 10000
#define FDIM 128
#define HDIM 64
#define NEDGES 320000
#define M_EDGES (NEDGES + N_NODES)   // 330000 (with self-loops)

typedef __attribute__((ext_vector_type(8))) short short8;   // 8 bf16
typedef __attribute__((ext_vector_type(4))) float floatx4;

#define AL_STR 10048     // floats, per-layer stride for N-sized arrays (SZ_N4/4)
#define H_STR  640064    // floats, per-layer stride for h (N*64 + pad)
#define H2_STR 20032     // floats, per-layer stride for h2 (N*2 + pad)

__device__ __forceinline__ float lrelu(float v, float s){ return v >= 0.f ? v : s*v; }

// ---------------- CSR count + train-mask sum ----------------
__global__ void k_count(const int* __restrict__ ep, const int* __restrict__ eh,
                        int* __restrict__ ptr_p, int* __restrict__ ptr_h,
                        const int* __restrict__ tm, float* __restrict__ misc){
  int idx = blockIdx.x*blockDim.x + threadIdx.x;
  int c = (idx < N_NODES) ? (tm[idx] > 0) : 0;
  #pragma unroll
  for (int off=32; off; off>>=1) c += __shfl_down(c, off);
  if ((threadIdx.x & 63) == 0 && c > 0) atomicAdd(&misc[1], (float)c);
  if (idx >= 2*M_EDGES) return;
  int list = idx >= M_EDGES;
  int e = idx - list*M_EDGES;
  const int* el = list ? eh : ep;
  int* ptr = list ? ptr_h : ptr_p;
  int dst = (e < NEDGES) ? el[NEDGES + e] : (e - NEDGES);
  atomicAdd(&ptr[dst+1], 1);
}

// ---------------- exclusive scan: one block per edge-list ----------------
__global__ void k_scan(int* __restrict__ ptr_p, int* __restrict__ cur_p,
                       int* __restrict__ ptr_h, int* __restrict__ cur_h){
  __shared__ int wsum[4];
  __shared__ int carry;
  int t = threadIdx.x, wid = t>>6, lane = t&63;
  int* ptr = blockIdx.x ? ptr_h : ptr_p;
  int* cur = blockIdx.x ? cur_h : cur_p;
  if (t == 0) carry = 0;
  __syncthreads();
  for (int base = 0; base <= N_NODES; base += 256){
    int i = base + t;
    int v = (i <= N_NODES) ? ptr[i] : 0;
    int sc = v;
    #pragma unroll
    for (int off=1; off<64; off<<=1){ int u = __shfl_up(sc, off); if (lane >= off) sc += u; }
    if (lane == 63) wsum[wid] = sc;
    __syncthreads();
    int wo = 0;
    for (int w = 0; w < wid; ++w) wo += wsum[w];
    int val = carry + wo + sc;
    if (i <= N_NODES) ptr[i] = val;
    if (i <  N_NODES) cur[i] = val;
    __syncthreads();
    if (t == 0) carry += wsum[0]+wsum[1]+wsum[2]+wsum[3];
    __syncthreads();
  }
}

__global__ void k_fill(const int* __restrict__ ep, const int* __restrict__ eh,
                       int* __restrict__ cur_p, int* __restrict__ cur_h,
                       int* __restrict__ src_p, int* __restrict__ src_h){
  int idx = blockIdx.x*blockDim.x + threadIdx.x;
  if (idx >= 2*M_EDGES) return;
  int list = idx >= M_EDGES;
  int e = idx - list*M_EDGES;
  const int* el = list ? eh : ep;
  int* cur  = list ? cur_h : cur_p;
  int* sarr = list ? src_h : src_p;
  int src, dst;
  if (e < NEDGES){ src = el[e]; dst = el[NEDGES+e]; } else { src = dst = e - NEDGES; }
  int pos = atomicAdd(&cur[dst], 1);
  sarr[pos] = src;
}

// ---------------- layer-fused: h = x@W1, al/ar (grid.y = layer) ----------------
__global__ __launch_bounds__(256) void k_gemm1(const float* __restrict__ x, const float* __restrict__ W1,
    const float* __restrict__ asrc, const float* __restrict__ adst,
    float* __restrict__ h, float* __restrict__ al, float* __restrict__ ar){
  int l = blockIdx.y;
  const float* W = W1 + (size_t)l*FDIM*HDIM;
  const float* as = asrc + l*HDIM;
  const float* ad = adst + l*HDIM;
  float* hl  = h  + (size_t)l*H_STR;
  float* all = al + (size_t)l*AL_STR;
  float* arl = ar + (size_t)l*AL_STR;
  int wid = threadIdx.x>>6, lane = threadIdx.x&63;
  int r = blockIdx.x*4 + wid;
  if (r >= N_NODES) return;
  const float* xr = x + (size_t)r*FDIM;
  float xv0 = xr[lane], xv1 = xr[64+lane];
  float acc = 0.f;
  #pragma unroll 16
  for (int k=0;k<64;k++) acc = fmaf(__shfl(xv0,k), W[k*HDIM+lane], acc);
  #pragma unroll 16
  for (int k=0;k<64;k++) acc = fmaf(__shfl(xv1,k), W[(64+k)*HDIM+lane], acc);
  hl[(size_t)r*HDIM + lane] = acc;
  float pa = acc*as[lane], pb = acc*ad[lane];
  #pragma unroll
  for (int off=32; off; off>>=1){ pa += __shfl_down(pa,off); pb += __shfl_down(pb,off); }
  if (lane==0){ all[r]=pa; arl[r]=pb; }
}

// ---- layer-fused GAT1: single-pass online softmax+aggregate, affine, lrelu, GEMM2 ----
__global__ __launch_bounds__(256) void k_gat1(const int* __restrict__ ptr_p, const int* __restrict__ src_p,
    const int* __restrict__ ptr_h, const int* __restrict__ src_h,
    const float* __restrict__ al, const float* __restrict__ ar, const float* __restrict__ h,
    const float* __restrict__ b1, const float* __restrict__ gam, const float* __restrict__ bet,
    const float* __restrict__ W2, const float* __restrict__ asrc2, const float* __restrict__ adst2,
    float* __restrict__ h2, float* __restrict__ al2, float* __restrict__ ar2){
  int l = blockIdx.y;
  const int* ptr    = (l & 1) ? ptr_h : ptr_p;
  const int* srcarr = (l & 1) ? src_h : src_p;
  const float* all = al + (size_t)l*AL_STR;
  const float* arl = ar + (size_t)l*AL_STR;
  const float* hl  = h  + (size_t)l*H_STR;
  const float* b1l = b1 + l*HDIM;
  const float* gl  = gam + l*HDIM;
  const float* bl  = bet + l*HDIM;
  const float* W   = W2 + (size_t)l*HDIM*2;
  int wid = threadIdx.x>>6, lane = threadIdx.x&63;
  int n = blockIdx.x*4 + wid;
  if (n >= N_NODES) return;
  int s0 = ptr[n], s1 = ptr[n+1];
  float arn = arl[n];
  float m = -3.0e38f, s = 0.f, acc = 0.f;
  for (int base = s0; base < s1; base += 64){
    int cnt = min(64, s1 - base);
    int sj = 0; float aval = -3.0e38f;
    if (lane < cnt){ sj = srcarr[base + lane]; aval = lrelu(all[sj] + arn, 0.2f); }
    // chunk max (butterfly)
    float cm = aval;
    #pragma unroll
    for (int off=32; off; off>>=1) cm = fmaxf(cm, __shfl_xor(cm, off));
    float mn = fmaxf(m, cm);
    float r  = __expf(m - mn);
    s *= r; acc *= r; m = mn;
    // pipelined sequential aggregation (lanes = H columns)
    int   sjt = __shfl(sj, 0);
    float hv  = hl[(size_t)sjt*HDIM + lane];
    for (int t = 0; t < cnt; ++t){
      float a = __shfl(aval, t);
      float w = __expf(a - m);
      float hc = hv;
      if (t + 1 < cnt){ int sn = __shfl(sj, t+1); hv = hl[(size_t)sn*HDIM + lane]; }
      s  += (lane == 0) ? w : 0.f;   // s identical on all lanes anyway; keep per-lane
      s  -= (lane == 0) ? 0.f : 0.f;
      acc = fmaf(w, hc, acc);
      if (lane != 0) s += w;          // keep s consistent on every lane
    }
  }
  float hid = acc/(s + 1e-16f) + b1l[lane];
  hid = hid*(gl[lane]*0.9999950000374997f) + bl[lane];   // gamma/sqrt(1+1e-5)
  hid = lrelu(hid, 0.01f);
  float t0 = hid*W[lane*2+0], t1 = hid*W[lane*2+1];
  #pragma unroll
  for (int off=32; off; off>>=1){ t0 += __shfl_down(t0,off); t1 += __shfl_down(t1,off); }
  if (lane==0){
    float* h2l = h2 + (size_t)l*H2_STR;
    h2l[n*2+0] = t0; h2l[n*2+1] = t1;
    al2[(size_t)l*AL_STR + n] = t0*asrc2[l*2+0] + t1*asrc2[l*2+1];
    ar2[(size_t)l*AL_STR + n] = t0*adst2[l*2+0] + t1*adst2[l*2+1];
  }
}

// ---- layer-fused GAT2: lane-parallel single-pass online softmax, log_softmax, loss ----
__global__ __launch_bounds__(256) void k_gat2(const int* __restrict__ ptr_p, const int* __restrict__ src_p,
    const int* __restrict__ ptr_h, const int* __restrict__ src_h,
    const float* __restrict__ al2, const float* __restrict__ ar2, const float* __restrict__ h2,
    const float* __restrict__ b2, const int* __restrict__ y, const int* __restrict__ tm,
    float* __restrict__ np_arr, float* __restrict__ misc){
  __shared__ float lbuf[4];
  int l = blockIdx.y;
  const int* ptr    = (l & 1) ? ptr_h : ptr_p;
  const int* srcarr = (l & 1) ? src_h : src_p;
  const float* alL = al2 + (size_t)l*AL_STR;
  const float* arL = ar2 + (size_t)l*AL_STR;
  const float* h2l = h2  + (size_t)l*H2_STR;
  int wid = threadIdx.x>>6, lane = threadIdx.x&63;
  int n = blockIdx.x*4 + wid;
  float lval = 0.f;
  if (n < N_NODES){
    int s0 = ptr[n], s1 = ptr[n+1];
    float arn = arL[n];
    float m = -3.0e38f, s = 0.f, a0 = 0.f, a1 = 0.f;
    for (int idx = s0+lane; idx < s1; idx += 64){
      int sj = srcarr[idx];
      float a = lrelu(alL[sj] + arn, 0.2f);
      float2 hv = *(const float2*)(h2l + sj*2);
      float mn = fmaxf(m, a);
      float r  = __expf(m - mn);
      float w  = __expf(a - mn);
      s  = s*r + w;
      a0 = a0*r + w*hv.x;
      a1 = a1*r + w*hv.y;
      m = mn;
    }
    #pragma unroll
    for (int off=32; off; off>>=1){
      float mo = __shfl_xor(m, off), so = __shfl_xor(s, off);
      float b0 = __shfl_xor(a0, off), b1v = __shfl_xor(a1, off);
      float mn = fmaxf(m, mo);
      float r1 = __expf(m - mn), r2 = __expf(mo - mn);
      s  = s*r1 + so*r2;
      a0 = a0*r1 + b0*r2;
      a1 = a1*r1 + b1v*r2;
      m = mn;
    }
    if (lane == 0){
      float sden = s + 1e-16f;
      float o0 = a0/sden + b2[l*2+0], o1 = a1/sden + b2[l*2+1];
      float mx = fmaxf(o0, o1);
      float lse = mx + logf(__expf(o0-mx) + __expf(o1-mx));
      float lp0 = o0 - lse, lp1 = o1 - lse;
      np_arr[(size_t)l*AL_STR + n] = __expf(lp1);
      float pick = (y[n] == 0) ? lp0 : lp1;
      lval = (tm[n] > 0) ? -pick : 0.f;
    }
  }
  if (lane == 0) lbuf[wid] = lval;
  __syncthreads();
  if (threadIdx.x == 0){
    float tt = lbuf[0]+lbuf[1]+lbuf[2]+lbuf[3];
    if (tt != 0.f) atomicAdd(&misc[0], tt);
  }
}

// ---------------- ex (bf16) + row sums + feature gates ----------------
__global__ __launch_bounds__(256) void k_ex(const float* __restrict__ x,
                                            const float* __restrict__ logit_p, const float* __restrict__ emb_w,
                                            __hip_bfloat16* __restrict__ exb, float* __restrict__ denom,
                                            float* __restrict__ keepsw, float* __restrict__ pw_out){
  __shared__ float ksw[128];
  int t = threadIdx.x;
  if (t < 128){
    const float EPSF = 2.2204460492503131e-16f;
    float p = 1.f/(1.f + __expf(-logit_p[t]));
    float approx = logf(p + EPSF) - logf(1.f - p + EPSF);
    float keep = 1.f - 1.f/(1.f + __expf(-approx*10.f));
    float v = keep * (1.f/(1.f + __expf(-emb_w[t])));
    ksw[t] = v;
    if (blockIdx.x == 0){ keepsw[t] = v; pw_out[t] = 1.f - p; }
  }
  __syncthreads();
  int wid = t>>6, lane = t&63;
  int r = blockIdx.x*4 + wid;
  if (r >= N_NODES) return;
  const float* xr = x + (size_t)r*FDIM;
  float v0 = xr[lane]*ksw[lane];
  float v1 = xr[64+lane]*ksw[64+lane];
  exb[(size_t)r*FDIM + lane]      = __float2bfloat16(v0);
  exb[(size_t)r*FDIM + 64 + lane] = __float2bfloat16(v1);
  float sr = v0 + v1;
  #pragma unroll
  for (int off=32; off; off>>=1) sr += __shfl_down(sr, off);
  if (lane == 0) denom[r] = sr + 1e-6f;
}

__global__ void k_npfin(const float* __restrict__ np_arr, const float* __restrict__ denom,
                        const float* __restrict__ misc, float* __restrict__ out_np,
                        float* __restrict__ out_loss, float* __restrict__ scale){
  int i = blockIdx.x*blockDim.x + threadIdx.x;
  if (i < N_NODES){
    float npv = 0.25f*(np_arr[i] + np_arr[AL_STR+i] + np_arr[2*AL_STR+i] + np_arr[3*AL_STR+i]);
    out_np[i] = npv;
    scale[i] = (2.f*npv - 1.f)/denom[i];
  }
  if (i == 0) out_loss[0] = misc[0]/(misc[1]*4.f);
}

// ---------------- w2[f] = keepsw[f] * sum_j x[j,f]*scale[j] ----------------
__global__ __launch_bounds__(256) void k_w2(const float* __restrict__ x, const float* __restrict__ keepsw,
                                            const float* __restrict__ scale, float* __restrict__ w2){
  __shared__ float sred[256];
  int t = threadIdx.x, f = t & 127, half = t >> 7;
  float acc = 0.f;
  for (int j2 = blockIdx.x; j2 < N_NODES/2; j2 += gridDim.x){
    int j = j2*2 + half;
    acc = fmaf(x[(size_t)j*FDIM + f], scale[j], acc);
  }
  sred[t] = acc;
  __syncthreads();
  if (t < 128) atomicAdd(&w2[f], (sred[t] + sred[t+128])*keepsw[f]);
}

// ---------------- norm1[i] = sigmoid(ex_i . w2) ----------------
__global__ __launch_bounds__(256) void k_t(const float* __restrict__ x, const float* __restrict__ keepsw,
                                           const float* __restrict__ w2, float* __restrict__ out_norm1){
  int wid = threadIdx.x>>6, lane = threadIdx.x&63;
  int r = blockIdx.x*4 + wid;
  if (r >= N_NODES) return;
  const float* xr = x + (size_t)r*FDIM;
  float tv = xr[lane]*keepsw[lane]*w2[lane] + xr[64+lane]*keepsw[64+lane]*w2[64+lane];
  #pragma unroll
  for (int off=32; off; off>>=1) tv += __shfl_down(tv, off);
  if (lane == 0) out_norm1[r] = 1.f/(1.f + __expf(-tv));
}

// ---------------- graph = (ex @ ex^T) * (1/denom[j]) via bf16 MFMA ----------------
__global__ __launch_bounds__(256) void k_graph(const __hip_bfloat16* __restrict__ exb,
                                               const float* __restrict__ denom,
                                               float* __restrict__ gout){
  __shared__ ushort As[128*128];
  __shared__ ushort Bs[128*128];
  int t = threadIdx.x;
  int bi = blockIdx.y, bj = blockIdx.x;
  const ushort* exu = (const ushort*)exb;
  for (int it = 0; it < 8; ++it){
    int idx = it*256 + t;
    int r = idx >> 4;
    int c = idx & 15;
    int csw = c ^ (r & 15);
    int4 va = make_int4(0,0,0,0), vb = make_int4(0,0,0,0);
    int gi = bi*128 + r;
    int gj = bj*128 + r;
    if (gi < N_NODES) va = *(const int4*)(exu + (size_t)gi*FDIM + c*8);
    if (gj < N_NODES) vb = *(const int4*)(exu + (size_t)gj*FDIM + c*8);
    *(int4*)(&As[r*128 + csw*8]) = va;
    *(int4*)(&Bs[r*128 + csw*8]) = vb;
  }
  __syncthreads();
  int wid = t>>6, lane = t&63;
  int wy = wid>>1, wx = wid&1;
  int lr = lane&15, lq = lane>>4;
  floatx4 acc[4][4];
  #pragma unroll
  for (int a=0;a<4;a++)
    #pragma unroll
    for (int b=0;b<4;b++) acc[a][b] = (floatx4){0.f,0.f,0.f,0.f};
  #pragma unroll
  for (int ks = 0; ks < 4; ++ks){
    int cidx = ks*4 + lq;
    short8 af[4], bf[4];
    #pragma unroll
    for (int a=0;a<4;a++){
      int row = wy*64 + a*16 + lr;
      af[a] = *(const short8*)(&As[row*128 + (cidx ^ lr)*8]);
    }
    #pragma unroll
    for (int b=0;b<4;b++){
      int row = wx*64 + b*16 + lr;
      bf[b] = *(const short8*)(&Bs[row*128 + (cidx ^ lr)*8]);
    }
    #pragma unroll
    for (int a=0;a<4;a++)
      #pragma unroll
      for (int b=0;b<4;b++)
        acc[a][b] = __builtin_amdgcn_mfma_f32_16x16x32_bf16(af[a], bf[b], acc[a][b], 0, 0, 0);
  }
  #pragma unroll
  for (int b=0;b<4;b++){
    int j = bj*128 + wx*64 + b*16 + lr;
    float rden = (j < N_NODES) ? 1.f/denom[j] : 0.f;
    #pragma unroll
    for (int a=0;a<4;a++){
      int ibase = bi*128 + wy*64 + a*16 + lq*4;
      #pragma unroll
      for (int rr=0; rr<4; ++rr){
        int i = ibase + rr;
        if (i < N_NODES && j < N_NODES)
          gout[(size_t)i*N_NODES + j] = acc[a][b][rr]*rden;
      }
    }
  }
}

// ---------------- host launch ----------------
extern "C" void kernel_launch(void* const* d_in, const int* in_sizes, int n_in,
                              void* d_out, int out_size, void* d_ws, size_t ws_size,
                              hipStream_t stream) {
  (void)in_sizes; (void)n_in; (void)out_size;
  const float* x      = (const float*)d_in[0];
  const int*   y      = (const int*)  d_in[1];
  const int*   tmask  = (const int*)  d_in[2];
  const int*   ep     = (const int*)  d_in[3];
  const int*   eh     = (const int*)  d_in[4];
  const float* W1     = (const float*)d_in[5];
  const float* asrc1  = (const float*)d_in[6];
  const float* adst1  = (const float*)d_in[7];
  const float* b1     = (const float*)d_in[8];
  const float* gam    = (const float*)d_in[9];
  const float* bet    = (const float*)d_in[10];
  const float* W2     = (const float*)d_in[11];
  const float* asrc2  = (const float*)d_in[12];
  const float* adst2  = (const float*)d_in[13];
  const float* b2     = (const float*)d_in[14];
  const float* emb_w  = (const float*)d_in[15];
  const float* logitp = (const float*)d_in[16];

  constexpr size_t SZ_N4 = 40192;                 // (N+1)*4 padded to 256B
  constexpr size_t OFF_PTR_P = 0;
  constexpr size_t OFF_PTR_H = OFF_PTR_P + SZ_N4;
  constexpr size_t OFF_MISC  = OFF_PTR_H + SZ_N4; // misc[0]=loss, misc[1]=masksum
  constexpr size_t OFF_W2V   = OFF_MISC + 256;
  constexpr size_t OFF_KSW   = OFF_MISC + 768;
  constexpr size_t ZBYTES    = OFF_MISC + 1280;   // zero ptr_p/ptr_h/misc/w2v in one memset
  constexpr size_t OFF_CUR_P = ZBYTES;
  constexpr size_t OFF_CUR_H = OFF_CUR_P + SZ_N4;
  constexpr size_t OFF_SRC_P = OFF_CUR_H + SZ_N4;
  constexpr size_t OFF_SRC_H = OFF_SRC_P + 1320192;          // M_EDGES*4 padded
  constexpr size_t OFF_H     = OFF_SRC_H + 1320192;          // 4 layers x H_STR
  constexpr size_t OFF_AL    = OFF_H  + 4*(size_t)H_STR*4;
  constexpr size_t OFF_AR    = OFF_AL + 4*SZ_N4;
  constexpr size_t OFF_H2    = OFF_AR + 4*SZ_N4;
  constexpr size_t OFF_AL2   = OFF_H2 + 4*(size_t)H2_STR*4;
  constexpr size_t OFF_AR2   = OFF_AL2 + 4*SZ_N4;
  constexpr size_t OFF_NP    = OFF_AR2 + 4*SZ_N4;
  constexpr size_t OFF_EXB   = OFF_NP  + 4*SZ_N4;
  constexpr size_t OFF_DEN   = OFF_EXB + 2560256;            // N*128*2 padded
  constexpr size_t OFF_SCALE = OFF_DEN + SZ_N4;
  constexpr size_t WS_NEED   = OFF_SCALE + SZ_N4;
  if (ws_size < WS_NEED) return;

  char* ws = (char*)d_ws;
  int*   ptr_p  = (int*)  (ws + OFF_PTR_P);
  int*   ptr_h  = (int*)  (ws + OFF_PTR_H);
  float* misc   = (float*)(ws + OFF_MISC);
  float* w2v    = (float*)(ws + OFF_W2V);
  float* keepsw = (float*)(ws + OFF_KSW);
  int*   cur_p  = (int*)  (ws + OFF_CUR_P);
  int*   cur_h  = (int*)  (ws + OFF_CUR_H);
  int*   src_p  = (int*)  (ws + OFF_SRC_P);
  int*   src_h  = (int*)  (ws + OFF_SRC_H);
  float* hbuf   = (float*)(ws + OFF_H);
  float* al     = (float*)(ws + OFF_AL);
  float* ar     = (float*)(ws + OFF_AR);
  float* h2     = (float*)(ws + OFF_H2);
  float* al2    = (float*)(ws + OFF_AL2);
  float* ar2    = (float*)(ws + OFF_AR2);
  float* np_arr = (float*)(ws + OFF_NP);
  __hip_bfloat16* exb = (__hip_bfloat16*)(ws + OFF_EXB);
  float* denom  = (float*)(ws + OFF_DEN);
  float* scale  = (float*)(ws + OFF_SCALE);

  float* out       = (float*)d_out;
  float* out_np    = out;                // 10000
  float* out_loss  = out + 10000;        // 1
  float* out_norm  = out + 10001;        // 10000
  float* out_graph = out + 20001;        // 1e8
  float* out_pw    = out + 100020001;    // 128

  hipMemsetAsync(ws, 0, ZBYTES, stream);

  int eg = (2*M_EDGES + 255)/256;
  k_count<<<eg, 256, 0, stream>>>(ep, eh, ptr_p, ptr_h, tmask, misc);
  k_scan<<<2, 256, 0, stream>>>(ptr_p, cur_p, ptr_h, cur_h);
  k_fill<<<eg, 256, 0, stream>>>(ep, eh, cur_p, cur_h, src_p, src_h);

  dim3 lg(2500, 4);
  k_gemm1<<<lg, 256, 0, stream>>>(x, W1, asrc1, adst1, hbuf, al, ar);
  k_gat1<<<lg, 256, 0, stream>>>(ptr_p, src_p, ptr_h, src_h, al, ar, hbuf,
                                 b1, gam, bet, W2, asrc2, adst2, h2, al2, ar2);
  k_gat2<<<lg, 256, 0, stream>>>(ptr_p, src_p, ptr_h, src_h, al2, ar2, h2,
                                 b2, y, tmask, np_arr, misc);

  k_ex<<<2500, 256, 0, stream>>>(x, logitp, emb_w, exb, denom, keepsw, out_pw);
  k_npfin<<<40, 256, 0, stream>>>(np_arr, denom, misc, out_np, out_loss, scale);
  k_w2<<<64, 256, 0, stream>>>(x, keepsw, scale, w2v);
  k_t<<<2500, 256, 0, stream>>>(x, keepsw, w2v, out_norm);

  dim3 gg((N_NODES + 127)/128, (N_NODES + 127)/128);
  k_graph<<<gg, 256, 0, stream>>>(exb, denom, out_graph);
}